// Round 1
// baseline (263.130 us; speedup 1.0000x reference)
//
#include <hip/hip_runtime.h>

#define H 1024
#define E 8
#define BLK 256
#define CAP 5120       // int(1.25 * 4096 * 8 / 8)
#define FBLK 1024
#define TPW 16         // tokens per wave

typedef float f32x4 __attribute__((ext_vector_type(4)));

// ---------------------------------------------------------------------------
// Kernel 1 (rewrite): latency-bound fix.
// Old design: one wave-load touched 4 scattered 256B segments (4 token slots
// 8KB apart) and kept only ~2 loads in flight -> 1.7 TB/s effective, 78.6us
// (counters: HBM 11%, VALU 16%, LDS-conflict 0, occ 41% -> no saturated pipe
// = latency-bound).
// New design: lane l permanently owns row floats {4l+256q, q=0..3}, so each
// wave-load is 64 lanes x 16B = 1KB CONTIGUOUS (one quarter of ONE token
// row) -- the exact pattern of the 6.3 TB/s copy ceiling. The w slices lane
// l needs are then FIXED: w[e][q] = rw[e][256q+4l..+3] lives in 128 VGPRs,
// loaded once per wave. Main loop: ZERO LDS, ZERO barriers, 2-token-deep
// prefetch (8 x 1KB in flight/wave). __launch_bounds__(256,2) frees the
// allocator up to 256 VGPR -> ~8 waves/CU -> ~64KB in flight per CU.
// Dot completion: 6-step full-64 butterfly (48 shfl + 48 add per token;
// LDS-pipe ~50%, VALU ~30% at full stream rate -- both under the roofline).
// Epilogue: token tok0+l owned by lane l (softmax/top2/renorm/stores),
// 16 owner lanes in parallel, 32B-contiguous f32x4 stores.
// ---------------------------------------------------------------------------
__global__ __launch_bounds__(BLK, 2) void router_kernel(
    const float* __restrict__ hs,
    const float* __restrict__ rw,
    float* __restrict__ dispatch,
    float* __restrict__ probs_out,
    float* __restrict__ partial)   // [16][nb] slot-major
{
    __shared__ float red[4][16][16];   // 4 KB only (occupancy no longer LDS-bound)

    const int tid  = threadIdx.x;
    const int wave = tid >> 6;
    const int lane = tid & 63;
    const size_t tok0 = ((size_t)blockIdx.x * (BLK / 64) + wave) * TPW;
    const float* h0 = hs + tok0 * H + 4 * lane;

    // Prefetch tokens 0 and 1 (8 x 1KB contiguous loads) before w loads,
    // so the HBM round-trip overlaps the (L2-hit) w staging.
    f32x4 A0[4], A1[4];
#pragma unroll
    for (int q = 0; q < 4; ++q) A0[q] = *(const f32x4*)(h0 + q * 256);
#pragma unroll
    for (int q = 0; q < 4; ++q) A1[q] = *(const f32x4*)(h0 + H + q * 256);

    // w[e][q] covers rw[e][256q + 4*lane .. +3]; 32 x 1KB-contiguous loads,
    // L2-resident after the first blocks. 128 VGPRs, held for the kernel.
    f32x4 w[E][4];
#pragma unroll
    for (int e = 0; e < E; ++e)
#pragma unroll
        for (int q = 0; q < 4; ++q)
            w[e][q] = *(const f32x4*)(rw + e * H + q * 256 + 4 * lane);

    float mylog[E];   // owner-lane logits (lane l owns token tok0+l)
#pragma unroll
    for (int e = 0; e < E; ++e) mylog[e] = 0.f;

    const float* pnext = h0 + 2 * H;   // refill pointer (token t+2)

#pragma unroll 1   // rolled: ~600-instr body, I-cache friendly; indices static
    for (int t = 0; t < TPW; t += 2) {
        float acc0[E], acc1[E];
#pragma unroll
        for (int e = 0; e < E; ++e) { acc0[e] = 0.f; acc1[e] = 0.f; }

        // --- token t: consume A0, then refill A0 with token t+2 ---
#pragma unroll
        for (int e = 0; e < E; ++e)
#pragma unroll
            for (int q = 0; q < 4; ++q) {
                acc0[e] = fmaf(A0[q][0], w[e][q][0], acc0[e]);
                acc0[e] = fmaf(A0[q][1], w[e][q][1], acc0[e]);
                acc0[e] = fmaf(A0[q][2], w[e][q][2], acc0[e]);
                acc0[e] = fmaf(A0[q][3], w[e][q][3], acc0[e]);
            }
        if (t + 2 < TPW) {
#pragma unroll
            for (int q = 0; q < 4; ++q) A0[q] = *(const f32x4*)(pnext + q * 256);
        }

        // --- token t+1: consume A1, then refill A1 with token t+3 ---
#pragma unroll
        for (int e = 0; e < E; ++e)
#pragma unroll
            for (int q = 0; q < 4; ++q) {
                acc1[e] = fmaf(A1[q][0], w[e][q][0], acc1[e]);
                acc1[e] = fmaf(A1[q][1], w[e][q][1], acc1[e]);
                acc1[e] = fmaf(A1[q][2], w[e][q][2], acc1[e]);
                acc1[e] = fmaf(A1[q][3], w[e][q][3], acc1[e]);
            }
        if (t + 3 < TPW) {
#pragma unroll
            for (int q = 0; q < 4; ++q) A1[q] = *(const f32x4*)(pnext + H + q * 256);
        }
        pnext += 2 * H;

        // --- full-wave butterfly: every lane ends with the complete dots;
        //     owner lanes latch theirs via cndmask (no runtime indexing) ---
#pragma unroll
        for (int e = 0; e < E; ++e) {
            float v0 = acc0[e], v1 = acc1[e];
            v0 += __shfl_xor(v0, 1);  v1 += __shfl_xor(v1, 1);
            v0 += __shfl_xor(v0, 2);  v1 += __shfl_xor(v1, 2);
            v0 += __shfl_xor(v0, 4);  v1 += __shfl_xor(v1, 4);
            v0 += __shfl_xor(v0, 8);  v1 += __shfl_xor(v1, 8);
            v0 += __shfl_xor(v0, 16); v1 += __shfl_xor(v1, 16);
            v0 += __shfl_xor(v0, 32); v1 += __shfl_xor(v1, 32);
            mylog[e] = (lane == t)     ? v0 : mylog[e];
            mylog[e] = (lane == t + 1) ? v1 : mylog[e];
        }
    }

    // --- owner-lane epilogue (lanes >= TPW compute on zeros, results unused)
    float mx = mylog[0];
#pragma unroll
    for (int e = 1; e < E; ++e) mx = fmaxf(mx, mylog[e]);
    float p[E], s = 0.f;
#pragma unroll
    for (int e = 0; e < E; ++e) { p[e] = expf(mylog[e] - mx); s += p[e]; }
    const float inv = 1.f / s;
#pragma unroll
    for (int e = 0; e < E; ++e) p[e] *= inv;

    // top-2, strict >, lowest index on ties (lax.top_k semantics).
    // Track values in scalars -- no runtime-indexed arrays (scratch trap).
    int i1 = 0; float v1 = p[0];
#pragma unroll
    for (int e = 1; e < E; ++e) if (p[e] > v1) { v1 = p[e]; i1 = e; }
    int i2 = -1; float v2 = -1.f;
#pragma unroll
    for (int e = 0; e < E; ++e) {
        if (e == i1) continue;
        if (p[e] > v2) { v2 = p[e]; i2 = e; }
    }
    const float s12 = v1 + v2;
    const float w1 = v1 / s12;
    const float w2 = v2 / s12;

    float d[E];
#pragma unroll
    for (int e = 0; e < E; ++e)
        d[e] = (e == i1) ? w1 : ((e == i2) ? w2 : 0.f);

    f32x4 dv0 = {d[0], d[1], d[2], d[3]}, dv1 = {d[4], d[5], d[6], d[7]};
    f32x4 pv0 = {p[0], p[1], p[2], p[3]}, pv1 = {p[4], p[5], p[6], p[7]};

    if (lane < TPW) {
        const size_t tok = tok0 + lane;
        *(f32x4*)(dispatch  + tok * E)     = dv0;
        *(f32x4*)(dispatch  + tok * E + 4) = dv1;
        *(f32x4*)(probs_out + tok * E)     = pv0;
        *(f32x4*)(probs_out + tok * E + 4) = pv1;
        // slot layout: 0..7 = dispatch mass per expert, 8..15 = prob sums
        f32x4* dst = (f32x4*)&red[wave][lane][0];
        dst[0] = dv0; dst[1] = dv1; dst[2] = pv0; dst[3] = pv1;
    }
    __syncthreads();
    if (tid < 16) {
        float acc = 0.f;
#pragma unroll
        for (int wv = 0; wv < 4; ++wv)
            for (int l = 0; l < TPW; ++l) acc += red[wv][l][tid];
        partial[(size_t)tid * gridDim.x + blockIdx.x] = acc;   // slot-major
    }
}

// ---------------------------------------------------------------------------
// Kernel 2: reduce partials -> lb_loss; per-expert capacity enforcement
// (exact radix select, index-ordered ties). Early-exits when under capacity
// (always, in expectation: E[mass/expert]=4096 < 5120 -- insurance path).
// ---------------------------------------------------------------------------
__global__ __launch_bounds__(FBLK) void finalize_kernel(
    float* __restrict__ dispatch,
    const float* __restrict__ partial,
    int nb,
    float* __restrict__ lb_out,
    int N)
{
    const int e    = blockIdx.x;
    const int tid  = threadIdx.x;
    const int lane = tid & 63;
    const int wv   = tid >> 6;           // 16 waves -> 16 slots

    __shared__ float g[16];
    {
        float v = 0.f;
        for (int b = lane; b < nb; b += 64) v += partial[(size_t)wv * nb + b];
#pragma unroll
        for (int off = 32; off; off >>= 1) v += __shfl_xor(v, off);
        if (lane == 0) g[wv] = v;
    }
    __syncthreads();

    if (e == 0 && tid == 0) {
        float s = 0.f;
        for (int i = 0; i < E; ++i) s += g[i] * g[E + i];
        *lb_out = 0.01f * s / (float)N;
    }

    const float tpe = g[e];
    if (!(tpe > (float)CAP)) return;     // block-uniform

    __shared__ unsigned hist[256];
    __shared__ unsigned sh_prefix;
    __shared__ int sh_k;

    unsigned prefix = 0;
    int k = CAP;

    for (int round = 0; round < 4; ++round) {
        const int shift = 24 - 8 * round;
        for (int i = tid; i < 256; i += FBLK) hist[i] = 0;
        __syncthreads();
        const unsigned mhi = (round == 0) ? 0u : (0xFFFFFFFFu << (shift + 8));
        for (int i = tid; i < N; i += FBLK) {
            const unsigned bits = __float_as_uint(dispatch[(size_t)i * E + e]);
            if ((bits & mhi) == (prefix & mhi))
                atomicAdd(&hist[(bits >> shift) & 255u], 1u);
        }
        __syncthreads();
        if (tid == 0) {
            int cum = 0;
            int d = 255;
            for (; d > 0; --d) {
                const int h = (int)hist[d];
                if (cum + h >= k) break;
                cum += h;
            }
            sh_prefix = prefix | ((unsigned)d << shift);
            sh_k = k - cum;
        }
        __syncthreads();
        prefix = sh_prefix;
        k = sh_k;
        __syncthreads();
    }

    const unsigned T = prefix;
    const unsigned r = (unsigned)k;

    __shared__ unsigned wave_cnt[FBLK / 64];
    __shared__ unsigned running;
    if (tid == 0) running = 0;
    __syncthreads();

    for (int base = 0; base < N; base += FBLK) {
        const int i = base + tid;
        const unsigned bits = __float_as_uint(dispatch[(size_t)i * E + e]);
        const bool eq = (bits == T);
        const unsigned long long bal = __ballot(eq);
        if (lane == 0) wave_cnt[wv] = (unsigned)__popcll(bal);
        __syncthreads();
        unsigned before = running;
        for (int w = 0; w < wv; ++w) before += wave_cnt[w];
        const unsigned rank = before + (unsigned)__popcll(bal & ((1ull << lane) - 1ull));
        const bool keep = (bits > T) || (eq && rank < r);
        if (!keep) dispatch[(size_t)i * E + e] = 0.f;
        __syncthreads();
        if (tid == 0) {
            unsigned tot = 0;
            for (int w = 0; w < FBLK / 64; ++w) tot += wave_cnt[w];
            running += tot;
        }
        __syncthreads();
    }
}

// ---------------------------------------------------------------------------
extern "C" void kernel_launch(void* const* d_in, const int* in_sizes, int n_in,
                              void* d_out, int out_size, void* d_ws, size_t ws_size,
                              hipStream_t stream)
{
    const float* hs = (const float*)d_in[0];
    const float* rw = (const float*)d_in[1];
    const int n_tokens = in_sizes[0] / H;          // 32768

    float* dispatch = (float*)d_out;               // [N*E]
    float* lb       = dispatch + (size_t)n_tokens * E;
    float* probs    = lb + 1;                      // [N*E]
    float* partial  = (float*)d_ws;                // [16][nb] fp32, fully written

    const int nb = n_tokens / (4 * TPW);           // 512 blocks, 64 tokens/block
    router_kernel<<<nb, BLK, 0, stream>>>(hs, rw, dispatch, probs, partial);
    finalize_kernel<<<E, FBLK, 0, stream>>>(dispatch, partial, nb, lb, n_tokens);
}

// Round 3
// 246.747 us; speedup vs baseline: 1.0664x; 1.0664x over previous
//
#include <hip/hip_runtime.h>

#define H 1024
#define E 8
#define BLK 256
#define CAP 5120       // int(1.25 * 4096 * 8 / 8)
#define FBLK 1024
#define TPW 8          // tokens per wave

typedef float f32x4 __attribute__((ext_vector_type(4)));

// ---------------------------------------------------------------------------
// Kernel 1: contiguous-stream GEMV, register-light.
// R1 post-mortem: w[8][4] in VGPRs demanded ~190 regs vs 128 allocated ->
// scratch spill (WRITE_SIZE 2.6->34.5MB, FETCH +30MB, VALUBusy 6.7%).
// Fix: w lives in LDS (32KB); lane l reads w[e][q] at (e*1024+q*256+4l) --
// 16B/lane contiguous ds_read_b128 = the conflict-free m134 pattern, reused
// across 2 tokens. VGPR demand ~85, __launch_bounds__(256,4) caps 128 -> no
// spill. TPW=8 -> 1024 blocks = 4 blocks/CU = 16 waves/CU.
// hs loads stay 1KB-contiguous per wave (lane l owns floats {4l+256q} of one
// row), depth-2 token prefetch staggered through the q-loop.
// Reduction: reduce-scatter (masks 1,2,4 halve the expert set with
// keep/send selects, masks 8,16,32 plain add) -> lane 8g+e ends holding
// logit(token g, expert e): 10 shfl/token vs 48 for the full butterfly
// (halves LDS-pipe pressure; aggregate LDS ~13us < 21us memory floor).
// Epilogue: all 64 lanes active; softmax/top2 via 3-step group butterflies;
// dispatch/probs stores are one dword/lane, 256B contiguous per wave.
// (R2 was an infra failure -- container acquisition died; kernel re-audited
// for OOB/divergent-barrier/scratch and resubmitted unchanged.)
// ---------------------------------------------------------------------------
__global__ __launch_bounds__(BLK, 4) void router_kernel(
    const float* __restrict__ hs,
    const float* __restrict__ rw,
    float* __restrict__ dispatch,
    float* __restrict__ probs_out,
    float* __restrict__ partial)   // [16][nb] slot-major
{
    __shared__ float w_lds[E * H];   // 32 KB
    __shared__ float red[4][16];

    const int tid  = threadIdx.x;
    const int wave = tid >> 6;
    const int lane = tid & 63;
    const int g    = lane >> 3;      // token group within wave (0..7)
    const int eo   = lane & 7;       // owned expert
    const size_t tok0 = ((size_t)blockIdx.x * (BLK / 64) + wave) * TPW;
    const float* h0 = hs + tok0 * H + 4 * lane;

    // depth-2 token prefetch (8 x 1KB contiguous wave-loads), issued before
    // the w staging so the HBM round-trip overlaps it
    f32x4 A0[4], A1[4];
#pragma unroll
    for (int q = 0; q < 4; ++q) A0[q] = *(const f32x4*)(h0 + q * 256);
#pragma unroll
    for (int q = 0; q < 4; ++q) A1[q] = *(const f32x4*)(h0 + H + q * 256);

    for (int i = tid; i < E * H / 4; i += BLK)
        ((f32x4*)w_lds)[i] = ((const f32x4*)rw)[i];
    __syncthreads();

    const int b0 = lane & 1, b1 = (lane >> 1) & 1, b2 = (lane >> 2) & 1;

    // reduce-scatter: input a[8] = per-lane partials for one token; output =
    // full dot for expert (lane&7), replicated across the 8 lane-groups.
    // keep/send selects use only static indices (no scratch trap).
    auto rscatter = [&](const float* a) -> float {
        float r0 = b0 ? a[1] : a[0], s0 = b0 ? a[0] : a[1];
        float r1 = b0 ? a[3] : a[2], s1 = b0 ? a[2] : a[3];
        float r2 = b0 ? a[5] : a[4], s2 = b0 ? a[4] : a[5];
        float r3 = b0 ? a[7] : a[6], s3 = b0 ? a[6] : a[7];
        r0 += __shfl_xor(s0, 1); r1 += __shfl_xor(s1, 1);
        r2 += __shfl_xor(s2, 1); r3 += __shfl_xor(s3, 1);
        float t0 = b1 ? r1 : r0, u0 = b1 ? r0 : r1;
        float t1 = b1 ? r3 : r2, u1 = b1 ? r2 : r3;
        t0 += __shfl_xor(u0, 2); t1 += __shfl_xor(u1, 2);
        float v = b2 ? t1 : t0, x = b2 ? t0 : t1;
        v += __shfl_xor(x, 4);
        v += __shfl_xor(v, 8);
        v += __shfl_xor(v, 16);
        v += __shfl_xor(v, 32);
        return v;                 // logit for expert 4*b2+2*b1+b0 = lane&7
    };

    float mylog = 0.f;            // latched logit for (token tok0+g, expert eo)
    const float* pnext = h0 + 2 * H;

#pragma unroll
    for (int t = 0; t < TPW; t += 2) {
        float acc0[E], acc1[E];
#pragma unroll
        for (int e = 0; e < E; ++e) { acc0[e] = 0.f; acc1[e] = 0.f; }

#pragma unroll
        for (int q = 0; q < 4; ++q) {
            const float* wb = w_lds + q * 256 + 4 * lane;
#pragma unroll
            for (int e = 0; e < E; ++e) {
                const f32x4 wv = *(const f32x4*)(wb + e * H);
                acc0[e] = fmaf(A0[q][0], wv[0], acc0[e]);
                acc0[e] = fmaf(A0[q][1], wv[1], acc0[e]);
                acc0[e] = fmaf(A0[q][2], wv[2], acc0[e]);
                acc0[e] = fmaf(A0[q][3], wv[3], acc0[e]);
                acc1[e] = fmaf(A1[q][0], wv[0], acc1[e]);
                acc1[e] = fmaf(A1[q][1], wv[1], acc1[e]);
                acc1[e] = fmaf(A1[q][2], wv[2], acc1[e]);
                acc1[e] = fmaf(A1[q][3], wv[3], acc1[e]);
            }
            // staggered depth-2 refill: A*[q] dead after this q-phase
            if (t + 2 < TPW) {
                A0[q] = *(const f32x4*)(pnext + q * 256);
                A1[q] = *(const f32x4*)(pnext + H + q * 256);
            }
        }
        if (t + 2 < TPW) pnext += 2 * H;

        const float u0v = rscatter(acc0);
        const float u1v = rscatter(acc1);
        mylog = (g == t)     ? u0v : mylog;
        mylog = (g == t + 1) ? u1v : mylog;
    }

    // --- epilogue: softmax + top-2 within each 8-lane group (masks 1,2,4) ---
    float mx = mylog;
    mx = fmaxf(mx, __shfl_xor(mx, 1));
    mx = fmaxf(mx, __shfl_xor(mx, 2));
    mx = fmaxf(mx, __shfl_xor(mx, 4));
    float pe = expf(mylog - mx);
    float s = pe;
    s += __shfl_xor(s, 1); s += __shfl_xor(s, 2); s += __shfl_xor(s, 4);
    pe = pe / s;

    // top-1 (max, lowest index on ties — lax.top_k semantics)
    float v1 = pe; int i1 = eo;
#pragma unroll
    for (int m = 1; m <= 4; m <<= 1) {
        const float ov = __shfl_xor(v1, m);
        const int   oi = __shfl_xor(i1, m);
        const bool take = (ov > v1) || (ov == v1 && oi < i1);
        v1 = take ? ov : v1; i1 = take ? oi : i1;
    }
    // top-2: exclude winner (probs > 0 always, so -1 is a safe sentinel)
    float v2 = (eo == i1) ? -1.f : pe; int i2 = eo;
#pragma unroll
    for (int m = 1; m <= 4; m <<= 1) {
        const float ov = __shfl_xor(v2, m);
        const int   oi = __shfl_xor(i2, m);
        const bool take = (ov > v2) || (ov == v2 && oi < i2);
        v2 = take ? ov : v2; i2 = take ? oi : i2;
    }
    const float s12 = v1 + v2;
    const float d = (eo == i1) ? (v1 / s12) : ((eo == i2) ? (v2 / s12) : 0.f);

    // stores: one dword/lane, 256B contiguous per wave
    dispatch[tok0 * E + lane]  = d;
    probs_out[tok0 * E + lane] = pe;

    // per-wave slot sums: slot e = dispatch mass, slot 8+e = prob sum
    float ds = d, ps = pe;
    ds += __shfl_xor(ds, 8);  ps += __shfl_xor(ps, 8);
    ds += __shfl_xor(ds, 16); ps += __shfl_xor(ps, 16);
    ds += __shfl_xor(ds, 32); ps += __shfl_xor(ps, 32);
    if (lane < 8) { red[wave][eo] = ds; red[wave][8 + eo] = ps; }
    __syncthreads();
    if (tid < 16) {
        const float acc = red[0][tid] + red[1][tid] + red[2][tid] + red[3][tid];
        partial[(size_t)tid * gridDim.x + blockIdx.x] = acc;   // slot-major
    }
}

// ---------------------------------------------------------------------------
// Kernel 2: reduce partials -> lb_loss; per-expert capacity enforcement
// (exact radix select, index-ordered ties). Early-exits when under capacity
// (always, in expectation: E[mass/expert]=4096 < 5120 -- insurance path).
// ---------------------------------------------------------------------------
__global__ __launch_bounds__(FBLK) void finalize_kernel(
    float* __restrict__ dispatch,
    const float* __restrict__ partial,
    int nb,
    float* __restrict__ lb_out,
    int N)
{
    const int e    = blockIdx.x;
    const int tid  = threadIdx.x;
    const int lane = tid & 63;
    const int wv   = tid >> 6;           // 16 waves -> 16 slots

    __shared__ float g[16];
    {
        float v = 0.f;
        for (int b = lane; b < nb; b += 64) v += partial[(size_t)wv * nb + b];
#pragma unroll
        for (int off = 32; off; off >>= 1) v += __shfl_xor(v, off);
        if (lane == 0) g[wv] = v;
    }
    __syncthreads();

    if (e == 0 && tid == 0) {
        float s = 0.f;
        for (int i = 0; i < E; ++i) s += g[i] * g[E + i];
        *lb_out = 0.01f * s / (float)N;
    }

    const float tpe = g[e];
    if (!(tpe > (float)CAP)) return;     // block-uniform

    __shared__ unsigned hist[256];
    __shared__ unsigned sh_prefix;
    __shared__ int sh_k;

    unsigned prefix = 0;
    int k = CAP;

    for (int round = 0; round < 4; ++round) {
        const int shift = 24 - 8 * round;
        for (int i = tid; i < 256; i += FBLK) hist[i] = 0;
        __syncthreads();
        const unsigned mhi = (round == 0) ? 0u : (0xFFFFFFFFu << (shift + 8));
        for (int i = tid; i < N; i += FBLK) {
            const unsigned bits = __float_as_uint(dispatch[(size_t)i * E + e]);
            if ((bits & mhi) == (prefix & mhi))
                atomicAdd(&hist[(bits >> shift) & 255u], 1u);
        }
        __syncthreads();
        if (tid == 0) {
            int cum = 0;
            int d = 255;
            for (; d > 0; --d) {
                const int h = (int)hist[d];
                if (cum + h >= k) break;
                cum += h;
            }
            sh_prefix = prefix | ((unsigned)d << shift);
            sh_k = k - cum;
        }
        __syncthreads();
        prefix = sh_prefix;
        k = sh_k;
        __syncthreads();
    }

    const unsigned T = prefix;
    const unsigned r = (unsigned)k;

    __shared__ unsigned wave_cnt[FBLK / 64];
    __shared__ unsigned running;
    if (tid == 0) running = 0;
    __syncthreads();

    for (int base = 0; base < N; base += FBLK) {
        const int i = base + tid;
        const unsigned bits = __float_as_uint(dispatch[(size_t)i * E + e]);
        const bool eq = (bits == T);
        const unsigned long long bal = __ballot(eq);
        if (lane == 0) wave_cnt[wv] = (unsigned)__popcll(bal);
        __syncthreads();
        unsigned before = running;
        for (int w = 0; w < wv; ++w) before += wave_cnt[w];
        const unsigned rank = before + (unsigned)__popcll(bal & ((1ull << lane) - 1ull));
        const bool keep = (bits > T) || (eq && rank < r);
        if (!keep) dispatch[(size_t)i * E + e] = 0.f;
        __syncthreads();
        if (tid == 0) {
            unsigned tot = 0;
            for (int w = 0; w < FBLK / 64; ++w) tot += wave_cnt[w];
            running += tot;
        }
        __syncthreads();
    }
}

// ---------------------------------------------------------------------------
extern "C" void kernel_launch(void* const* d_in, const int* in_sizes, int n_in,
                              void* d_out, int out_size, void* d_ws, size_t ws_size,
                              hipStream_t stream)
{
    const float* hs = (const float*)d_in[0];
    const float* rw = (const float*)d_in[1];
    const int n_tokens = in_sizes[0] / H;          // 32768

    float* dispatch = (float*)d_out;               // [N*E]
    float* lb       = dispatch + (size_t)n_tokens * E;
    float* probs    = lb + 1;                      // [N*E]
    float* partial  = (float*)d_ws;                // [16][nb] fp32, fully written

    const int nb = n_tokens / (4 * TPW);           // 1024 blocks, 32 tokens each
    router_kernel<<<nb, BLK, 0, stream>>>(hs, rw, dispatch, probs, partial);
    finalize_kernel<<<E, FBLK, 0, stream>>>(dispatch, partial, nb, lb, n_tokens);
}